// Round 5
// baseline (636.093 us; speedup 1.0000x reference)
//
#include <hip/hip_runtime.h>

#define N_NODESC 50000
#define N_EDGESC 800000
#define N_GRAPHSC 512
#define DF 128
#define BN_EPSF 1e-5f

typedef _Float16 half8 __attribute__((ext_vector_type(8)));
typedef _Float16 half4v __attribute__((ext_vector_type(4)));
typedef _Float16 half2v __attribute__((ext_vector_type(2)));
typedef float floatx4 __attribute__((ext_vector_type(4)));

// ---------------- CSR build ----------------
__global__ __launch_bounds__(256) void k_count(const int* __restrict__ dst, int* __restrict__ counts) {
    int e = blockIdx.x * 256 + threadIdx.x;
    if (e < N_EDGESC) atomicAdd(&counts[dst[e]], 1);
}

__global__ __launch_bounds__(1024) void k_scan1(int* __restrict__ off, int* __restrict__ partials) {
    __shared__ int sh[1024];
    int t = threadIdx.x;
    int i = blockIdx.x * 1024 + t;
    int v = (i < N_NODESC) ? off[i] : 0;
    sh[t] = v;
    __syncthreads();
    for (int ofs = 1; ofs < 1024; ofs <<= 1) {
        int u = (t >= ofs) ? sh[t - ofs] : 0;
        __syncthreads();
        sh[t] += u;
        __syncthreads();
    }
    if (i < N_NODESC) off[i] = sh[t] - v;  // local exclusive
    if (t == 1023) partials[blockIdx.x] = sh[1023];
}

__global__ __launch_bounds__(64) void k_scan2(int* __restrict__ partials, int nparts) {
    __shared__ int sh[64];
    int t = threadIdx.x;
    sh[t] = (t < nparts) ? partials[t] : 0;
    __syncthreads();
    for (int ofs = 1; ofs < 64; ofs <<= 1) {
        int u = (t >= ofs) ? sh[t - ofs] : 0;
        __syncthreads();
        sh[t] += u;
        __syncthreads();
    }
    if (t < nparts) partials[t] = sh[t];
}

__global__ __launch_bounds__(1024) void k_scan3(int* __restrict__ off, const int* __restrict__ partials,
                                                int* __restrict__ cursor) {
    int t = threadIdx.x;
    int i = blockIdx.x * 1024 + t;
    if (i < N_NODESC) {
        int base = blockIdx.x ? partials[blockIdx.x - 1] : 0;
        int o = off[i] + base;
        off[i] = o;
        cursor[i] = o;
    }
    if (i == 0) off[N_NODESC] = N_EDGESC;
}

__global__ __launch_bounds__(256) void k_scatter(const int* __restrict__ src, const int* __restrict__ dst,
                                                 int* __restrict__ cursor, int* __restrict__ csr) {
    int e = blockIdx.x * 256 + threadIdx.x;
    if (e < N_EDGESC) {
        int d = dst[e];
        int pos = atomicAdd(&cursor[d], 1);
        csr[pos] = src[e];
    }
}

// ---------------- x fp32 -> fp16 ----------------
__global__ __launch_bounds__(256) void k_convX(const float* __restrict__ x, _Float16* __restrict__ h) {
    int i4 = blockIdx.x * 256 + threadIdx.x;
    if (i4 >= N_NODESC * DF / 4) return;
    float4 v = ((const float4*)x)[i4];
    half4v o;
    o[0] = (_Float16)v.x; o[1] = (_Float16)v.y; o[2] = (_Float16)v.z; o[3] = (_Float16)v.w;
    ((half4v*)h)[i4] = o;
}

// ---------------- weight repack: fp32 [k][n] -> fp16 B-fragment order ----------------
__global__ __launch_bounds__(256) void k_convW(const float* __restrict__ W1, const float* __restrict__ W2,
                                               half8* __restrict__ wf) {
    int t = blockIdx.x * 256 + threadIdx.x;
    if (t >= 6 * 2048) return;
    int m = t >> 11;
    int p = t & 2047;
    int ntile = p >> 8;
    int ks = (p >> 6) & 3;
    int l = p & 63;
    int n = ntile * 16 + (l & 15);
    int kb = ks * 32 + (l >> 4) * 8;
    const float* W = (m < 3) ? (W1 + (size_t)m * DF * DF) : (W2 + (size_t)(m - 3) * DF * DF);
    half8 o;
#pragma unroll
    for (int j = 0; j < 8; j++) o[j] = (_Float16)W[(size_t)(kb + j) * DF + n];
    wf[t] = o;
}

// ---------------- gather + folded BN-affine/relu of previous layer ----------------
// MODE 0: Hin = fp16 x, identity transform. MODE 1: Hin = z_prev; h = relu(z*sc+of).
// wave-per-node (4 nodes / 256-thread block) for max TLP; lane owns 2 columns.
template <int MODE>
__global__ __launch_bounds__(256) void k_gather_bn(
    const _Float16* __restrict__ Hin, const int* __restrict__ off, const int* __restrict__ csr,
    const float* __restrict__ epsArr, int layer,
    const float* __restrict__ st_prev, const float* __restrict__ gprev, const float* __restrict__ bprev,
    _Float16* __restrict__ A)
{
    int n = blockIdx.x * 4 + (threadIdx.x >> 6);
    if (n >= N_NODESC) return;
    int lane = threadIdx.x & 63;

    float sc0 = 1.f, of0 = 0.f, sc1 = 1.f, of1 = 0.f;
    if (MODE == 1) {
        const float invN = 1.f / (float)N_NODESC;
        int c0 = 2 * lane, c1 = c0 + 1;
        float m0 = st_prev[c0] * invN;
        float v0 = st_prev[DF + c0] * invN - m0 * m0;
        sc0 = gprev[c0] * rsqrtf(v0 + BN_EPSF);
        of0 = bprev[c0] - m0 * sc0;
        float m1 = st_prev[c1] * invN;
        float v1 = st_prev[DF + c1] * invN - m1 * m1;
        sc1 = gprev[c1] * rsqrtf(v1 + BN_EPSF);
        of1 = bprev[c1] - m1 * sc1;
    }

    const half2v* Hr = (const half2v*)Hin;
    size_t base = (size_t)n * 64 + lane;
    half2v v = Hr[base];
    float e1 = 1.0f + epsArr[layer];
    float h0, h1;
    if (MODE == 1) {
        h0 = fmaxf((float)v[0] * sc0 + of0, 0.f);
        h1 = fmaxf((float)v[1] * sc1 + of1, 0.f);
    } else {
        h0 = (float)v[0];
        h1 = (float)v[1];
    }
    float a0 = e1 * h0, a1 = e1 * h1;

    int s = off[n], t = off[n + 1];
    int k = s;
    for (; k + 8 <= t; k += 8) {
        int m[8];
#pragma unroll
        for (int j = 0; j < 8; j++) m[j] = csr[k + j];
        half2v u[8];
#pragma unroll
        for (int j = 0; j < 8; j++) u[j] = Hr[(size_t)m[j] * 64 + lane];
#pragma unroll
        for (int j = 0; j < 8; j++) {
            if (MODE == 1) {
                a0 += fmaxf((float)u[j][0] * sc0 + of0, 0.f);
                a1 += fmaxf((float)u[j][1] * sc1 + of1, 0.f);
            } else {
                a0 += (float)u[j][0];
                a1 += (float)u[j][1];
            }
        }
    }
    for (; k < t; k++) {
        half2v u = Hr[(size_t)csr[k] * 64 + lane];
        if (MODE == 1) {
            a0 += fmaxf((float)u[0] * sc0 + of0, 0.f);
            a1 += fmaxf((float)u[1] * sc1 + of1, 0.f);
        } else {
            a0 += (float)u[0];
            a1 += (float)u[1];
        }
    }
    half2v o;
    o[0] = (_Float16)a0;
    o[1] = (_Float16)a1;
    ((half2v*)A)[base] = o;
}

// ---------------- fused MLP1 -> MLP2 -> stats -> z ----------------
// Block = 4 waves x 16 rows; A frags from global, W frags from global (L2-hot),
// intermediate B tile in LDS touched only intra-wave (no __syncthreads).
#define TSTRIDE 136  // 128 + 8 halfs pad
__global__ __launch_bounds__(256) void k_gemm12(
    const _Float16* __restrict__ A,
    const half8* __restrict__ W1f, const float* __restrict__ b1,
    const half8* __restrict__ W2f, const float* __restrict__ b2,
    _Float16* __restrict__ Z, float* __restrict__ st_out)
{
    __shared__ _Float16 tile[64 * TSTRIDE];  // 17 KB
    const int tid = threadIdx.x;
    const int wave = tid >> 6, lane = tid & 63;
    const int q = lane >> 4, c = lane & 15;
    const int myrow = wave * 16 + c;
    const int grow = blockIdx.x * 64 + myrow;
    const bool rowok = grow < N_NODESC;

    half8 zf = {};
    half8 af[4];
#pragma unroll
    for (int ks = 0; ks < 4; ks++)
        af[ks] = rowok ? *(const half8*)(A + (size_t)grow * DF + ks * 32 + q * 8) : zf;

    floatx4 acc[8];
#pragma unroll
    for (int nt = 0; nt < 8; nt++) acc[nt] = (floatx4)(0.0f);
#pragma unroll
    for (int ks = 0; ks < 4; ks++) {
#pragma unroll
        for (int nt = 0; nt < 8; nt++) {
            half8 wfr = W1f[(nt * 4 + ks) * 64 + lane];
            acc[nt] = __builtin_amdgcn_mfma_f32_16x16x32_f16(af[ks], wfr, acc[nt], 0, 0, 0);
        }
    }

    // epilogue 1: bias + relu -> fp16 -> LDS (rows wave*16+q*4+r; intra-wave only)
    const int rbase = wave * 16 + q * 4;
#pragma unroll
    for (int nt = 0; nt < 8; nt++) {
        float b = b1[nt * 16 + c];
#pragma unroll
        for (int r = 0; r < 4; r++) {
            float vv = fmaxf(acc[nt][r] + b, 0.f);
            tile[(rbase + r) * TSTRIDE + nt * 16 + c] = (_Float16)vv;
        }
    }

    half8 bf[4];
#pragma unroll
    for (int ks = 0; ks < 4; ks++)
        bf[ks] = *(const half8*)&tile[myrow * TSTRIDE + ks * 32 + q * 8];

    floatx4 acc2[8];
#pragma unroll
    for (int nt = 0; nt < 8; nt++) acc2[nt] = (floatx4)(0.0f);
#pragma unroll
    for (int ks = 0; ks < 4; ks++) {
#pragma unroll
        for (int nt = 0; nt < 8; nt++) {
            half8 wfr = W2f[(nt * 4 + ks) * 64 + lane];
            acc2[nt] = __builtin_amdgcn_mfma_f32_16x16x32_f16(bf[ks], wfr, acc2[nt], 0, 0, 0);
        }
    }

    // epilogue 2: bias, fp32 stats (pre-rounding), z-tile, coalesced store
    float s1[8], s2[8];
    const int growbase = blockIdx.x * 64 + rbase;
#pragma unroll
    for (int nt = 0; nt < 8; nt++) {
        float b = b2[nt * 16 + c];
        float ls = 0.f, lq = 0.f;
#pragma unroll
        for (int r = 0; r < 4; r++) {
            float vv = acc2[nt][r] + b;
            if (growbase + r < N_NODESC) {
                ls += vv;
                lq += vv * vv;
            }
            tile[(rbase + r) * TSTRIDE + nt * 16 + c] = (_Float16)vv;
        }
        s1[nt] = ls;
        s2[nt] = lq;
    }

#pragma unroll
    for (int i = 0; i < 4; i++) {
        int lr = wave * 16 + i * 4 + (lane >> 4);
        int gr = blockIdx.x * 64 + lr;
        half8 vz = *(const half8*)&tile[lr * TSTRIDE + (lane & 15) * 8];
        if (gr < N_NODESC)
            *(half8*)&Z[(size_t)gr * DF + (lane & 15) * 8] = vz;
    }

#pragma unroll
    for (int nt = 0; nt < 8; nt++) {
        s1[nt] += __shfl_xor(s1[nt], 16);
        s1[nt] += __shfl_xor(s1[nt], 32);
        s2[nt] += __shfl_xor(s2[nt], 16);
        s2[nt] += __shfl_xor(s2[nt], 32);
    }
    if (q == 0) {
#pragma unroll
        for (int nt = 0; nt < 8; nt++) {
            atomicAdd(&st_out[nt * 16 + c], s1[nt]);
            atomicAdd(&st_out[DF + nt * 16 + c], s2[nt]);
        }
    }
}

// ---------------- global mean pool with folded BN affine (last layer, no relu) ----------------
static __device__ int lbound(const int* __restrict__ a, int n, int key) {
    int lo = 0, hi = n;
    while (lo < hi) {
        int mid = (lo + hi) >> 1;
        if (a[mid] < key) lo = mid + 1; else hi = mid;
    }
    return lo;
}

__global__ __launch_bounds__(128) void k_pool(const _Float16* __restrict__ Z, const int* __restrict__ batch,
                                              const float* __restrict__ st, const float* __restrict__ gamma,
                                              const float* __restrict__ beta, float* __restrict__ out) {
    __shared__ int bnds[2];
    int g = blockIdx.x, c = threadIdx.x;
    if (threadIdx.x == 0) {
        bnds[0] = lbound(batch, N_NODESC, g);
        bnds[1] = lbound(batch, N_NODESC, g + 1);
    }
    __syncthreads();
    const float invN = 1.f / (float)N_NODESC;
    float m = st[c] * invN;
    float v = st[DF + c] * invN - m * m;
    float sc = gamma[c] * rsqrtf(v + BN_EPSF);
    float of = beta[c] - m * sc;
    int lo = bnds[0], hi = bnds[1];
    float s = 0.f;
    for (int r = lo; r < hi; r++) s += (float)Z[(size_t)r * DF + c];
    int cnt = hi - lo;
    out[g * DF + c] = (cnt > 0) ? (s / (float)cnt) * sc + of : 0.f;
}

extern "C" void kernel_launch(void* const* d_in, const int* in_sizes, int n_in,
                              void* d_out, int out_size, void* d_ws, size_t ws_size,
                              hipStream_t stream) {
    const float* x     = (const float*)d_in[0];
    const int*   ei    = (const int*)d_in[1];   // (2, E): row0=src, row1=dst
    const int*   batch = (const int*)d_in[2];
    const float* W1    = (const float*)d_in[3];
    const float* b1    = (const float*)d_in[4];
    const float* W2    = (const float*)d_in[5];
    const float* b2    = (const float*)d_in[6];
    const float* eps   = (const float*)d_in[7];
    const float* gamma = (const float*)d_in[8];
    const float* beta  = (const float*)d_in[9];
    float* out = (float*)d_out;

    char* ws = (char*)d_ws;
    size_t o = 0;
    auto alloc = [&](size_t bytes) -> char* {
        char* p = ws + o;
        o += (bytes + 255) & ~(size_t)255;
        return p;
    };
    int* off       = (int*)alloc((N_NODESC + 1) * sizeof(int));
    int* cursor    = (int*)alloc(N_NODESC * sizeof(int));
    int* csr       = (int*)alloc(N_EDGESC * sizeof(int));
    int* partials  = (int*)alloc(64 * sizeof(int));
    float* st      = (float*)alloc(3 * 2 * DF * sizeof(float));   // st[l] = st + l*256
    half8* wf      = (half8*)alloc((size_t)6 * 2048 * sizeof(half8));
    _Float16* hbuf = (_Float16*)alloc((size_t)N_NODESC * DF * sizeof(_Float16));
    _Float16* abuf = (_Float16*)alloc((size_t)N_NODESC * DF * sizeof(_Float16));
    _Float16* za   = (_Float16*)alloc((size_t)N_NODESC * DF * sizeof(_Float16));
    _Float16* zb   = (_Float16*)alloc((size_t)N_NODESC * DF * sizeof(_Float16));
    (void)ws_size; (void)in_sizes; (void)n_in; (void)out_size;

    const int* srcA = ei;
    const int* dstA = ei + N_EDGESC;

    const int NB_SCAN = (N_NODESC + 1023) / 1024;  // 49

    // CSR build + st zero
    hipMemsetAsync(off, 0, (N_NODESC + 1) * sizeof(int), stream);
    hipMemsetAsync(st, 0, 3 * 2 * DF * sizeof(float), stream);
    k_count<<<(N_EDGESC + 255) / 256, 256, 0, stream>>>(dstA, off);
    k_scan1<<<NB_SCAN, 1024, 0, stream>>>(off, partials);
    k_scan2<<<1, 64, 0, stream>>>(partials, NB_SCAN);
    k_scan3<<<NB_SCAN, 1024, 0, stream>>>(off, partials, cursor);
    k_scatter<<<(N_EDGESC + 255) / 256, 256, 0, stream>>>(srcA, dstA, cursor, csr);

    // weight repack + x conversion
    k_convW<<<(6 * 2048 + 255) / 256, 256, 0, stream>>>(W1, W2, wf);
    k_convX<<<(N_NODESC * DF / 4 + 255) / 256, 256, 0, stream>>>(x, hbuf);

    const int GATHER_GRID = (N_NODESC + 3) / 4;   // 12500
    const int GEMM_GRID = (N_NODESC + 63) / 64;   // 782

    // layer 0
    k_gather_bn<0><<<GATHER_GRID, 256, 0, stream>>>(hbuf, off, csr, eps, 0,
                                                    nullptr, nullptr, nullptr, abuf);
    k_gemm12<<<GEMM_GRID, 256, 0, stream>>>(abuf, wf + 0 * 2048, b1 + 0 * DF,
                                            wf + 3 * 2048, b2 + 0 * DF, za, st + 0 * 256);
    // layer 1 (bn0+relu folded into gather)
    k_gather_bn<1><<<GATHER_GRID, 256, 0, stream>>>(za, off, csr, eps, 1,
                                                    st + 0 * 256, gamma + 0 * DF, beta + 0 * DF, abuf);
    k_gemm12<<<GEMM_GRID, 256, 0, stream>>>(abuf, wf + 1 * 2048, b1 + 1 * DF,
                                            wf + 4 * 2048, b2 + 1 * DF, zb, st + 1 * 256);
    // layer 2 (bn1+relu folded into gather)
    k_gather_bn<1><<<GATHER_GRID, 256, 0, stream>>>(zb, off, csr, eps, 2,
                                                    st + 1 * 256, gamma + 1 * DF, beta + 1 * DF, abuf);
    k_gemm12<<<GEMM_GRID, 256, 0, stream>>>(abuf, wf + 2 * 2048, b1 + 2 * DF,
                                            wf + 5 * 2048, b2 + 2 * DF, za, st + 2 * 256);
    // pool with folded bn2 (no relu)
    k_pool<<<N_GRAPHSC, DF, 0, stream>>>(za, batch, st + 2 * 256, gamma + 2 * DF, beta + 2 * DF, out);
}

// Round 6
// 470.352 us; speedup vs baseline: 1.3524x; 1.3524x over previous
//
#include <hip/hip_runtime.h>

#define N_NODESC 50000
#define N_EDGESC 800000
#define N_GRAPHSC 512
#define DF 128
#define BN_EPSF 1e-5f
#define GEMM_BLOCKS 3125  // 50000 / 16 exactly
#define RED_BLOCKS 32

typedef _Float16 half8 __attribute__((ext_vector_type(8)));
typedef _Float16 half4v __attribute__((ext_vector_type(4)));
typedef _Float16 half2v __attribute__((ext_vector_type(2)));
typedef float floatx4 __attribute__((ext_vector_type(4)));

// ---------------- CSR build ----------------
__global__ __launch_bounds__(256) void k_count(const int* __restrict__ dst, int* __restrict__ counts) {
    int e = blockIdx.x * 256 + threadIdx.x;
    if (e < N_EDGESC) atomicAdd(&counts[dst[e]], 1);
}

__global__ __launch_bounds__(1024) void k_scan1(int* __restrict__ off, int* __restrict__ partials) {
    __shared__ int sh[1024];
    int t = threadIdx.x;
    int i = blockIdx.x * 1024 + t;
    int v = (i < N_NODESC) ? off[i] : 0;
    sh[t] = v;
    __syncthreads();
    for (int ofs = 1; ofs < 1024; ofs <<= 1) {
        int u = (t >= ofs) ? sh[t - ofs] : 0;
        __syncthreads();
        sh[t] += u;
        __syncthreads();
    }
    if (i < N_NODESC) off[i] = sh[t] - v;  // local exclusive
    if (t == 1023) partials[blockIdx.x] = sh[1023];
}

__global__ __launch_bounds__(64) void k_scan2(int* __restrict__ partials, int nparts) {
    __shared__ int sh[64];
    int t = threadIdx.x;
    sh[t] = (t < nparts) ? partials[t] : 0;
    __syncthreads();
    for (int ofs = 1; ofs < 64; ofs <<= 1) {
        int u = (t >= ofs) ? sh[t - ofs] : 0;
        __syncthreads();
        sh[t] += u;
        __syncthreads();
    }
    if (t < nparts) partials[t] = sh[t];
}

__global__ __launch_bounds__(1024) void k_scan3(int* __restrict__ off, const int* __restrict__ partials,
                                                int* __restrict__ cursor) {
    int t = threadIdx.x;
    int i = blockIdx.x * 1024 + t;
    if (i < N_NODESC) {
        int base = blockIdx.x ? partials[blockIdx.x - 1] : 0;
        int o = off[i] + base;
        off[i] = o;
        cursor[i] = o;
    }
    if (i == 0) off[N_NODESC] = N_EDGESC;
}

__global__ __launch_bounds__(256) void k_scatter(const int* __restrict__ src, const int* __restrict__ dst,
                                                 int* __restrict__ cursor, int* __restrict__ csr) {
    int e = blockIdx.x * 256 + threadIdx.x;
    if (e < N_EDGESC) {
        int d = dst[e];
        int pos = atomicAdd(&cursor[d], 1);
        csr[pos] = src[e];
    }
}

// ---------------- x fp32 -> fp16 ----------------
__global__ __launch_bounds__(256) void k_convX(const float* __restrict__ x, _Float16* __restrict__ h) {
    int i4 = blockIdx.x * 256 + threadIdx.x;
    if (i4 >= N_NODESC * DF / 4) return;
    float4 v = ((const float4*)x)[i4];
    half4v o;
    o[0] = (_Float16)v.x; o[1] = (_Float16)v.y; o[2] = (_Float16)v.z; o[3] = (_Float16)v.w;
    ((half4v*)h)[i4] = o;
}

// ---------------- weight repack: fp32 [k][n] -> fp16 B-fragment order ----------------
__global__ __launch_bounds__(256) void k_convW(const float* __restrict__ W1, const float* __restrict__ W2,
                                               half8* __restrict__ wf) {
    int t = blockIdx.x * 256 + threadIdx.x;
    if (t >= 6 * 2048) return;
    int m = t >> 11;
    int p = t & 2047;
    int ntile = p >> 8;
    int ks = (p >> 6) & 3;
    int l = p & 63;
    int n = ntile * 16 + (l & 15);
    int kb = ks * 32 + (l >> 4) * 8;
    const float* W = (m < 3) ? (W1 + (size_t)m * DF * DF) : (W2 + (size_t)(m - 3) * DF * DF);
    half8 o;
#pragma unroll
    for (int j = 0; j < 8; j++) o[j] = (_Float16)W[(size_t)(kb + j) * DF + n];
    wf[t] = o;
}

// ---------------- gather + folded BN-affine/relu of previous layer ----------------
// MODE 0: Hin = fp16 x, identity. MODE 1: Hin = z_prev; h = relu(z*sc+of).
// wave-per-node (4 nodes / 256-thread block); lane owns 2 columns; 8-edge unroll.
template <int MODE>
__global__ __launch_bounds__(256) void k_gather_bn(
    const _Float16* __restrict__ Hin, const int* __restrict__ off, const int* __restrict__ csr,
    const float* __restrict__ epsArr, int layer,
    const float* __restrict__ st_prev, const float* __restrict__ gprev, const float* __restrict__ bprev,
    _Float16* __restrict__ A)
{
    int n = blockIdx.x * 4 + (threadIdx.x >> 6);
    if (n >= N_NODESC) return;
    int lane = threadIdx.x & 63;

    float sc0 = 1.f, of0 = 0.f, sc1 = 1.f, of1 = 0.f;
    if (MODE == 1) {
        const float invN = 1.f / (float)N_NODESC;
        int c0 = 2 * lane, c1 = c0 + 1;
        float m0 = st_prev[c0] * invN;
        float v0 = st_prev[DF + c0] * invN - m0 * m0;
        sc0 = gprev[c0] * rsqrtf(v0 + BN_EPSF);
        of0 = bprev[c0] - m0 * sc0;
        float m1 = st_prev[c1] * invN;
        float v1 = st_prev[DF + c1] * invN - m1 * m1;
        sc1 = gprev[c1] * rsqrtf(v1 + BN_EPSF);
        of1 = bprev[c1] - m1 * sc1;
    }

    const half2v* Hr = (const half2v*)Hin;
    size_t base = (size_t)n * 64 + lane;
    half2v v = Hr[base];
    float e1 = 1.0f + epsArr[layer];
    float h0, h1;
    if (MODE == 1) {
        h0 = fmaxf((float)v[0] * sc0 + of0, 0.f);
        h1 = fmaxf((float)v[1] * sc1 + of1, 0.f);
    } else {
        h0 = (float)v[0];
        h1 = (float)v[1];
    }
    float a0 = e1 * h0, a1 = e1 * h1;

    int s = off[n], t = off[n + 1];
    int k = s;
    for (; k + 8 <= t; k += 8) {
        int m[8];
#pragma unroll
        for (int j = 0; j < 8; j++) m[j] = csr[k + j];
        half2v u[8];
#pragma unroll
        for (int j = 0; j < 8; j++) u[j] = Hr[(size_t)m[j] * 64 + lane];
#pragma unroll
        for (int j = 0; j < 8; j++) {
            if (MODE == 1) {
                a0 += fmaxf((float)u[j][0] * sc0 + of0, 0.f);
                a1 += fmaxf((float)u[j][1] * sc1 + of1, 0.f);
            } else {
                a0 += (float)u[j][0];
                a1 += (float)u[j][1];
            }
        }
    }
    for (; k < t; k++) {
        half2v u = Hr[(size_t)csr[k] * 64 + lane];
        if (MODE == 1) {
            a0 += fmaxf((float)u[0] * sc0 + of0, 0.f);
            a1 += fmaxf((float)u[1] * sc1 + of1, 0.f);
        } else {
            a0 += (float)u[0];
            a1 += (float)u[1];
        }
    }
    half2v o;
    o[0] = (_Float16)a0;
    o[1] = (_Float16)a1;
    ((half2v*)A)[base] = o;
}

// ---------------- fused MLP1 -> MLP2 -> partial stats -> z ----------------
// 128 threads = 2 waves per block; block owns 16 rows (grid = 3125, exact).
// Wave w computes cols [64w, 64w+64) of both GEMMs; 16x128 fp16 intermediate in LDS.
// Stats: per-block partial sums -> pb[block][256], reduced by k_redstats (no hot atomics).
#define TSTRIDE 136  // 128 + 8 halfs pad
__global__ __launch_bounds__(128) void k_gemm12(
    const _Float16* __restrict__ A,
    const half8* __restrict__ W1f, const float* __restrict__ b1,
    const half8* __restrict__ W2f, const float* __restrict__ b2,
    _Float16* __restrict__ Z, float* __restrict__ pb)
{
    __shared__ _Float16 tile[16 * TSTRIDE];  // 4.25 KB
    const int tid = threadIdx.x;
    const int w = tid >> 6, lane = tid & 63;
    const int q = lane >> 4, c = lane & 15;
    const int grow = blockIdx.x * 16 + c;  // always < 50000

    // A fragments: full K=128 for row grow
    half8 af[4];
#pragma unroll
    for (int ks = 0; ks < 4; ks++)
        af[ks] = *(const half8*)(A + (size_t)grow * DF + ks * 32 + q * 8);

    // gemm1: cols [64w, 64w+64)
    floatx4 acc[4];
#pragma unroll
    for (int j = 0; j < 4; j++) acc[j] = (floatx4)(0.0f);
#pragma unroll
    for (int ks = 0; ks < 4; ks++) {
#pragma unroll
        for (int j = 0; j < 4; j++) {
            int nt = w * 4 + j;
            half8 wfr = W1f[(nt * 4 + ks) * 64 + lane];
            acc[j] = __builtin_amdgcn_mfma_f32_16x16x32_f16(af[ks], wfr, acc[j], 0, 0, 0);
        }
    }

    // epilogue 1: bias + relu -> fp16 -> LDS rows q*4+r, cols [64w,64w+64)
#pragma unroll
    for (int j = 0; j < 4; j++) {
        int col = (w * 4 + j) * 16 + c;
        float b = b1[col];
#pragma unroll
        for (int r = 0; r < 4; r++) {
            float vv = fmaxf(acc[j][r] + b, 0.f);
            tile[(q * 4 + r) * TSTRIDE + col] = (_Float16)vv;
        }
    }
    __syncthreads();

    // gemm2: B fragments full K=128 from LDS
    half8 bf[4];
#pragma unroll
    for (int ks = 0; ks < 4; ks++)
        bf[ks] = *(const half8*)&tile[c * TSTRIDE + ks * 32 + q * 8];

    floatx4 acc2[4];
#pragma unroll
    for (int j = 0; j < 4; j++) acc2[j] = (floatx4)(0.0f);
#pragma unroll
    for (int ks = 0; ks < 4; ks++) {
#pragma unroll
        for (int j = 0; j < 4; j++) {
            int nt = w * 4 + j;
            half8 wfr = W2f[(nt * 4 + ks) * 64 + lane];
            acc2[j] = __builtin_amdgcn_mfma_f32_16x16x32_f16(bf[ks], wfr, acc2[j], 0, 0, 0);
        }
    }
    __syncthreads();  // all bf reads done before z overwrites tile

    // epilogue 2: bias, fp32 partial stats (pre-rounding), z -> LDS
    float s1[4], s2[4];
#pragma unroll
    for (int j = 0; j < 4; j++) {
        int col = (w * 4 + j) * 16 + c;
        float b = b2[col];
        float ls = 0.f, lq = 0.f;
#pragma unroll
        for (int r = 0; r < 4; r++) {
            float vv = acc2[j][r] + b;
            ls += vv;
            lq += vv * vv;
            tile[(q * 4 + r) * TSTRIDE + col] = (_Float16)vv;
        }
        s1[j] = ls;
        s2[j] = lq;
    }

    // reduce over the 4 q-groups (rows) -> q==0 lanes hold column totals
#pragma unroll
    for (int j = 0; j < 4; j++) {
        s1[j] += __shfl_xor(s1[j], 16);
        s1[j] += __shfl_xor(s1[j], 32);
        s2[j] += __shfl_xor(s2[j], 16);
        s2[j] += __shfl_xor(s2[j], 32);
    }
    if (q == 0) {
        float* pbb = pb + (size_t)blockIdx.x * 256;
#pragma unroll
        for (int j = 0; j < 4; j++) {
            int col = (w * 4 + j) * 16 + c;
            pbb[col] = s1[j];
            pbb[128 + col] = s2[j];
        }
    }
    __syncthreads();

    // coalesced z store: 16 rows x 256 B, 2 iterations
#pragma unroll
    for (int i = 0; i < 2; i++) {
        int lr = i * 8 + (tid >> 4);
        int col8 = tid & 15;
        half8 vz = *(const half8*)&tile[lr * TSTRIDE + col8 * 8];
        *(half8*)&Z[(size_t)(blockIdx.x * 16 + lr) * DF + col8 * 8] = vz;
    }
}

// ---------------- reduce per-block stat partials -> st (few atomics) ----------------
__global__ __launch_bounds__(256) void k_redstats(const float* __restrict__ pb, float* __restrict__ st) {
    int t = threadIdx.x;
    float s = 0.f;
    for (int r = blockIdx.x; r < GEMM_BLOCKS; r += RED_BLOCKS)
        s += pb[(size_t)r * 256 + t];
    atomicAdd(&st[t], s);
}

// ---------------- global mean pool with folded BN affine (last layer, no relu) ----------------
static __device__ int lbound(const int* __restrict__ a, int n, int key) {
    int lo = 0, hi = n;
    while (lo < hi) {
        int mid = (lo + hi) >> 1;
        if (a[mid] < key) lo = mid + 1; else hi = mid;
    }
    return lo;
}

__global__ __launch_bounds__(128) void k_pool(const _Float16* __restrict__ Z, const int* __restrict__ batch,
                                              const float* __restrict__ st, const float* __restrict__ gamma,
                                              const float* __restrict__ beta, float* __restrict__ out) {
    __shared__ int bnds[2];
    int g = blockIdx.x, c = threadIdx.x;
    if (threadIdx.x == 0) {
        bnds[0] = lbound(batch, N_NODESC, g);
        bnds[1] = lbound(batch, N_NODESC, g + 1);
    }
    __syncthreads();
    const float invN = 1.f / (float)N_NODESC;
    float m = st[c] * invN;
    float v = st[DF + c] * invN - m * m;
    float sc = gamma[c] * rsqrtf(v + BN_EPSF);
    float of = beta[c] - m * sc;
    int lo = bnds[0], hi = bnds[1];
    float s = 0.f;
    for (int r = lo; r < hi; r++) s += (float)Z[(size_t)r * DF + c];
    int cnt = hi - lo;
    out[g * DF + c] = (cnt > 0) ? (s / (float)cnt) * sc + of : 0.f;
}

extern "C" void kernel_launch(void* const* d_in, const int* in_sizes, int n_in,
                              void* d_out, int out_size, void* d_ws, size_t ws_size,
                              hipStream_t stream) {
    const float* x     = (const float*)d_in[0];
    const int*   ei    = (const int*)d_in[1];   // (2, E): row0=src, row1=dst
    const int*   batch = (const int*)d_in[2];
    const float* W1    = (const float*)d_in[3];
    const float* b1    = (const float*)d_in[4];
    const float* W2    = (const float*)d_in[5];
    const float* b2    = (const float*)d_in[6];
    const float* eps   = (const float*)d_in[7];
    const float* gamma = (const float*)d_in[8];
    const float* beta  = (const float*)d_in[9];
    float* out = (float*)d_out;

    char* ws = (char*)d_ws;
    size_t o = 0;
    auto alloc = [&](size_t bytes) -> char* {
        char* p = ws + o;
        o += (bytes + 255) & ~(size_t)255;
        return p;
    };
    int* off       = (int*)alloc((N_NODESC + 1) * sizeof(int));
    int* cursor    = (int*)alloc(N_NODESC * sizeof(int));
    int* csr       = (int*)alloc(N_EDGESC * sizeof(int));
    int* partials  = (int*)alloc(64 * sizeof(int));
    float* st      = (float*)alloc(3 * 2 * DF * sizeof(float));   // st[l] = st + l*256
    float* pb      = (float*)alloc((size_t)GEMM_BLOCKS * 256 * sizeof(float));  // 3.2 MB
    half8* wf      = (half8*)alloc((size_t)6 * 2048 * sizeof(half8));
    _Float16* hbuf = (_Float16*)alloc((size_t)N_NODESC * DF * sizeof(_Float16));
    _Float16* abuf = (_Float16*)alloc((size_t)N_NODESC * DF * sizeof(_Float16));
    _Float16* za   = (_Float16*)alloc((size_t)N_NODESC * DF * sizeof(_Float16));
    _Float16* zb   = (_Float16*)alloc((size_t)N_NODESC * DF * sizeof(_Float16));
    (void)ws_size; (void)in_sizes; (void)n_in; (void)out_size;

    const int* srcA = ei;
    const int* dstA = ei + N_EDGESC;

    const int NB_SCAN = (N_NODESC + 1023) / 1024;  // 49

    // CSR build + st zero
    hipMemsetAsync(off, 0, (N_NODESC + 1) * sizeof(int), stream);
    hipMemsetAsync(st, 0, 3 * 2 * DF * sizeof(float), stream);
    k_count<<<(N_EDGESC + 255) / 256, 256, 0, stream>>>(dstA, off);
    k_scan1<<<NB_SCAN, 1024, 0, stream>>>(off, partials);
    k_scan2<<<1, 64, 0, stream>>>(partials, NB_SCAN);
    k_scan3<<<NB_SCAN, 1024, 0, stream>>>(off, partials, cursor);
    k_scatter<<<(N_EDGESC + 255) / 256, 256, 0, stream>>>(srcA, dstA, cursor, csr);

    // weight repack + x conversion
    k_convW<<<(6 * 2048 + 255) / 256, 256, 0, stream>>>(W1, W2, wf);
    k_convX<<<(N_NODESC * DF / 4 + 255) / 256, 256, 0, stream>>>(x, hbuf);

    const int GATHER_GRID = (N_NODESC + 3) / 4;   // 12500

    // layer 0
    k_gather_bn<0><<<GATHER_GRID, 256, 0, stream>>>(hbuf, off, csr, eps, 0,
                                                    nullptr, nullptr, nullptr, abuf);
    k_gemm12<<<GEMM_BLOCKS, 128, 0, stream>>>(abuf, wf + 0 * 2048, b1 + 0 * DF,
                                              wf + 3 * 2048, b2 + 0 * DF, za, pb);
    k_redstats<<<RED_BLOCKS, 256, 0, stream>>>(pb, st + 0 * 256);
    // layer 1 (bn0+relu folded into gather)
    k_gather_bn<1><<<GATHER_GRID, 256, 0, stream>>>(za, off, csr, eps, 1,
                                                    st + 0 * 256, gamma + 0 * DF, beta + 0 * DF, abuf);
    k_gemm12<<<GEMM_BLOCKS, 128, 0, stream>>>(abuf, wf + 1 * 2048, b1 + 1 * DF,
                                              wf + 4 * 2048, b2 + 1 * DF, zb, pb);
    k_redstats<<<RED_BLOCKS, 256, 0, stream>>>(pb, st + 1 * 256);
    // layer 2 (bn1+relu folded into gather)
    k_gather_bn<1><<<GATHER_GRID, 256, 0, stream>>>(zb, off, csr, eps, 2,
                                                    st + 1 * 256, gamma + 1 * DF, beta + 1 * DF, abuf);
    k_gemm12<<<GEMM_BLOCKS, 128, 0, stream>>>(abuf, wf + 2 * 2048, b1 + 2 * DF,
                                              wf + 5 * 2048, b2 + 2 * DF, za, pb);
    k_redstats<<<RED_BLOCKS, 256, 0, stream>>>(pb, st + 2 * 256);
    // pool with folded bn2 (no relu)
    k_pool<<<N_GRAPHSC, DF, 0, stream>>>(za, batch, st + 2 * 256, gamma + 2 * DF, beta + 2 * DF, out);
}

// Round 7
// 444.794 us; speedup vs baseline: 1.4301x; 1.0575x over previous
//
#include <hip/hip_runtime.h>

#define N_NODESC 50000
#define N_EDGESC 800000
#define N_GRAPHSC 512
#define DF 128
#define BN_EPSF 1e-5f
#define GEMM_BLOCKS 3125  // 50000 / 16 exactly
#define RED_BLOCKS 32

// k_prep grid partition (exact, no guards)
#define PREP_COUNT_B 3125   // 800000 / 256
#define PREP_CONVX_B 3125   // 50000*128/8 / 256
#define PREP_CONVW_B 48     // 6*2048 / 256
#define PREP_TOTAL_B (PREP_COUNT_B + PREP_CONVX_B + PREP_CONVW_B + 1)

typedef _Float16 half8 __attribute__((ext_vector_type(8)));
typedef _Float16 half2v __attribute__((ext_vector_type(2)));
typedef float floatx4 __attribute__((ext_vector_type(4)));

// ---------------- fused prep: edge-count histogram | x->fp16 | W repack | st zero ----------------
__global__ __launch_bounds__(256) void k_prep(
    const int* __restrict__ dst, int* __restrict__ counts,
    const float* __restrict__ x, _Float16* __restrict__ h,
    const float* __restrict__ W1, const float* __restrict__ W2, half8* __restrict__ wf,
    float* __restrict__ st)
{
    int b = blockIdx.x;
    int tid = threadIdx.x;
    if (b < PREP_COUNT_B) {
        // count: histogram of dst (exact 800000 = 3125*256)
        int e = b * 256 + tid;
        atomicAdd(&counts[dst[e]], 1);
    } else if (b < PREP_COUNT_B + PREP_CONVX_B) {
        // convX: fp32 -> fp16, 8 elems/thread
        int i8 = (b - PREP_COUNT_B) * 256 + tid;
        const float4* x4 = (const float4*)x;
        float4 v0 = x4[i8 * 2], v1 = x4[i8 * 2 + 1];
        half8 o;
        o[0] = (_Float16)v0.x; o[1] = (_Float16)v0.y; o[2] = (_Float16)v0.z; o[3] = (_Float16)v0.w;
        o[4] = (_Float16)v1.x; o[5] = (_Float16)v1.y; o[6] = (_Float16)v1.z; o[7] = (_Float16)v1.w;
        ((half8*)h)[i8] = o;
    } else if (b < PREP_COUNT_B + PREP_CONVX_B + PREP_CONVW_B) {
        // convW: fp32 [k][n] -> fp16 B-fragment order
        int t = (b - PREP_COUNT_B - PREP_CONVX_B) * 256 + tid;
        int m = t >> 11;
        int p = t & 2047;
        int ntile = p >> 8;
        int ks = (p >> 6) & 3;
        int l = p & 63;
        int n = ntile * 16 + (l & 15);
        int kb = ks * 32 + (l >> 4) * 8;
        const float* W = (m < 3) ? (W1 + (size_t)m * DF * DF) : (W2 + (size_t)(m - 3) * DF * DF);
        half8 o;
#pragma unroll
        for (int j = 0; j < 8; j++) o[j] = (_Float16)W[(size_t)(kb + j) * DF + n];
        wf[t] = o;
    } else {
        // zero the 3 layers' stat accumulators (3 * 256 floats)
        if (tid < 256) {
            st[tid] = 0.f;
            st[256 + tid] = 0.f;
            st[512 + tid] = 0.f;
        }
    }
}

// ---------------- scan step 1: block-local exclusive scan, block totals -> partials ----------------
__global__ __launch_bounds__(1024) void k_scan1(int* __restrict__ off, int* __restrict__ partials) {
    __shared__ int sh[1024];
    int t = threadIdx.x;
    int i = blockIdx.x * 1024 + t;
    int v = (i < N_NODESC) ? off[i] : 0;
    sh[t] = v;
    __syncthreads();
    for (int ofs = 1; ofs < 1024; ofs <<= 1) {
        int u = (t >= ofs) ? sh[t - ofs] : 0;
        __syncthreads();
        sh[t] += u;
        __syncthreads();
    }
    if (i < N_NODESC) off[i] = sh[t] - v;  // local exclusive
    if (t == 1023) partials[blockIdx.x] = sh[1023];
}

// ---------------- scan finish: each block sums partials[<bid] itself, adds base, emits cursor ----------------
__global__ __launch_bounds__(1024) void k_scanfin(int* __restrict__ off, const int* __restrict__ partials,
                                                  int* __restrict__ cursor) {
    __shared__ int sbase;
    int t = threadIdx.x;
    if (t < 64) {
        int p = (t < blockIdx.x) ? partials[t] : 0;  // 49 partials max
#pragma unroll
        for (int ofs = 32; ofs > 0; ofs >>= 1) p += __shfl_down(p, ofs);
        if (t == 0) sbase = p;
    }
    __syncthreads();
    int base = sbase;
    int i = blockIdx.x * 1024 + t;
    if (i < N_NODESC) {
        int o = off[i] + base;
        off[i] = o;
        cursor[i] = o;
    }
    if (i == 0) off[N_NODESC] = N_EDGESC;
}

__global__ __launch_bounds__(256) void k_scatter(const int* __restrict__ src, const int* __restrict__ dst,
                                                 int* __restrict__ cursor, int* __restrict__ csr) {
    int e = blockIdx.x * 256 + threadIdx.x;  // exact 800000
    int d = dst[e];
    int pos = atomicAdd(&cursor[d], 1);
    csr[pos] = src[e];
}

// ---------------- gather + folded BN-affine/relu of previous layer ----------------
// MODE 0: Hin = fp16 x, identity. MODE 1: Hin = z_prev; h = relu(z*sc+of).
// wave-per-node (4 nodes / 256-thread block); lane owns 2 columns; 16-edge unroll.
template <int MODE>
__global__ __launch_bounds__(256) void k_gather_bn(
    const _Float16* __restrict__ Hin, const int* __restrict__ off, const int* __restrict__ csr,
    const float* __restrict__ epsArr, int layer,
    const float* __restrict__ st_prev, const float* __restrict__ gprev, const float* __restrict__ bprev,
    _Float16* __restrict__ A)
{
    int n = blockIdx.x * 4 + (threadIdx.x >> 6);  // grid exact: 12500*4 = 50000
    int lane = threadIdx.x & 63;

    float sc0 = 1.f, of0 = 0.f, sc1 = 1.f, of1 = 0.f;
    if (MODE == 1) {
        const float invN = 1.f / (float)N_NODESC;
        int c0 = 2 * lane, c1 = c0 + 1;
        float m0 = st_prev[c0] * invN;
        float v0 = st_prev[DF + c0] * invN - m0 * m0;
        sc0 = gprev[c0] * rsqrtf(v0 + BN_EPSF);
        of0 = bprev[c0] - m0 * sc0;
        float m1 = st_prev[c1] * invN;
        float v1 = st_prev[DF + c1] * invN - m1 * m1;
        sc1 = gprev[c1] * rsqrtf(v1 + BN_EPSF);
        of1 = bprev[c1] - m1 * sc1;
    }

    const half2v* Hr = (const half2v*)Hin;
    size_t base = (size_t)n * 64 + lane;
    half2v v = Hr[base];
    float e1 = 1.0f + epsArr[layer];
    float h0, h1;
    if (MODE == 1) {
        h0 = fmaxf((float)v[0] * sc0 + of0, 0.f);
        h1 = fmaxf((float)v[1] * sc1 + of1, 0.f);
    } else {
        h0 = (float)v[0];
        h1 = (float)v[1];
    }
    float a0 = e1 * h0, a1 = e1 * h1;

    int s = off[n], t = off[n + 1];
    int k = s;
    // 16-deep unroll: 16 outstanding row reads per wave (latency-hiding probe)
    for (; k + 16 <= t; k += 16) {
        int m[16];
#pragma unroll
        for (int j = 0; j < 16; j++) m[j] = csr[k + j];
        half2v u[16];
#pragma unroll
        for (int j = 0; j < 16; j++) u[j] = Hr[(size_t)m[j] * 64 + lane];
#pragma unroll
        for (int j = 0; j < 16; j++) {
            if (MODE == 1) {
                a0 += fmaxf((float)u[j][0] * sc0 + of0, 0.f);
                a1 += fmaxf((float)u[j][1] * sc1 + of1, 0.f);
            } else {
                a0 += (float)u[j][0];
                a1 += (float)u[j][1];
            }
        }
    }
    for (; k + 4 <= t; k += 4) {
        int m[4];
#pragma unroll
        for (int j = 0; j < 4; j++) m[j] = csr[k + j];
        half2v u[4];
#pragma unroll
        for (int j = 0; j < 4; j++) u[j] = Hr[(size_t)m[j] * 64 + lane];
#pragma unroll
        for (int j = 0; j < 4; j++) {
            if (MODE == 1) {
                a0 += fmaxf((float)u[j][0] * sc0 + of0, 0.f);
                a1 += fmaxf((float)u[j][1] * sc1 + of1, 0.f);
            } else {
                a0 += (float)u[j][0];
                a1 += (float)u[j][1];
            }
        }
    }
    for (; k < t; k++) {
        half2v u = Hr[(size_t)csr[k] * 64 + lane];
        if (MODE == 1) {
            a0 += fmaxf((float)u[0] * sc0 + of0, 0.f);
            a1 += fmaxf((float)u[1] * sc1 + of1, 0.f);
        } else {
            a0 += (float)u[0];
            a1 += (float)u[1];
        }
    }
    half2v o;
    o[0] = (_Float16)a0;
    o[1] = (_Float16)a1;
    ((half2v*)A)[base] = o;
}

// ---------------- fused MLP1 -> MLP2 -> partial stats -> z ----------------
// 128 threads = 2 waves per block; block owns 16 rows (grid = 3125, exact).
#define TSTRIDE 136  // 128 + 8 halfs pad
__global__ __launch_bounds__(128) void k_gemm12(
    const _Float16* __restrict__ A,
    const half8* __restrict__ W1f, const float* __restrict__ b1,
    const half8* __restrict__ W2f, const float* __restrict__ b2,
    _Float16* __restrict__ Z, float* __restrict__ pb)
{
    __shared__ _Float16 tile[16 * TSTRIDE];  // 4.25 KB
    const int tid = threadIdx.x;
    const int w = tid >> 6, lane = tid & 63;
    const int q = lane >> 4, c = lane & 15;
    const int grow = blockIdx.x * 16 + c;  // always < 50000

    half8 af[4];
#pragma unroll
    for (int ks = 0; ks < 4; ks++)
        af[ks] = *(const half8*)(A + (size_t)grow * DF + ks * 32 + q * 8);

    floatx4 acc[4];
#pragma unroll
    for (int j = 0; j < 4; j++) acc[j] = (floatx4)(0.0f);
#pragma unroll
    for (int ks = 0; ks < 4; ks++) {
#pragma unroll
        for (int j = 0; j < 4; j++) {
            int nt = w * 4 + j;
            half8 wfr = W1f[(nt * 4 + ks) * 64 + lane];
            acc[j] = __builtin_amdgcn_mfma_f32_16x16x32_f16(af[ks], wfr, acc[j], 0, 0, 0);
        }
    }

#pragma unroll
    for (int j = 0; j < 4; j++) {
        int col = (w * 4 + j) * 16 + c;
        float b = b1[col];
#pragma unroll
        for (int r = 0; r < 4; r++) {
            float vv = fmaxf(acc[j][r] + b, 0.f);
            tile[(q * 4 + r) * TSTRIDE + col] = (_Float16)vv;
        }
    }
    __syncthreads();

    half8 bf[4];
#pragma unroll
    for (int ks = 0; ks < 4; ks++)
        bf[ks] = *(const half8*)&tile[c * TSTRIDE + ks * 32 + q * 8];

    floatx4 acc2[4];
#pragma unroll
    for (int j = 0; j < 4; j++) acc2[j] = (floatx4)(0.0f);
#pragma unroll
    for (int ks = 0; ks < 4; ks++) {
#pragma unroll
        for (int j = 0; j < 4; j++) {
            int nt = w * 4 + j;
            half8 wfr = W2f[(nt * 4 + ks) * 64 + lane];
            acc2[j] = __builtin_amdgcn_mfma_f32_16x16x32_f16(bf[ks], wfr, acc2[j], 0, 0, 0);
        }
    }
    __syncthreads();  // all bf reads done before z overwrites tile

    float s1[4], s2[4];
#pragma unroll
    for (int j = 0; j < 4; j++) {
        int col = (w * 4 + j) * 16 + c;
        float b = b2[col];
        float ls = 0.f, lq = 0.f;
#pragma unroll
        for (int r = 0; r < 4; r++) {
            float vv = acc2[j][r] + b;
            ls += vv;
            lq += vv * vv;
            tile[(q * 4 + r) * TSTRIDE + col] = (_Float16)vv;
        }
        s1[j] = ls;
        s2[j] = lq;
    }

#pragma unroll
    for (int j = 0; j < 4; j++) {
        s1[j] += __shfl_xor(s1[j], 16);
        s1[j] += __shfl_xor(s1[j], 32);
        s2[j] += __shfl_xor(s2[j], 16);
        s2[j] += __shfl_xor(s2[j], 32);
    }
    if (q == 0) {
        float* pbb = pb + (size_t)blockIdx.x * 256;
#pragma unroll
        for (int j = 0; j < 4; j++) {
            int col = (w * 4 + j) * 16 + c;
            pbb[col] = s1[j];
            pbb[128 + col] = s2[j];
        }
    }
    __syncthreads();

#pragma unroll
    for (int i = 0; i < 2; i++) {
        int lr = i * 8 + (tid >> 4);
        int col8 = tid & 15;
        half8 vz = *(const half8*)&tile[lr * TSTRIDE + col8 * 8];
        *(half8*)&Z[(size_t)(blockIdx.x * 16 + lr) * DF + col8 * 8] = vz;
    }
}

// ---------------- reduce per-block stat partials -> st ----------------
__global__ __launch_bounds__(256) void k_redstats(const float* __restrict__ pb, float* __restrict__ st) {
    int t = threadIdx.x;
    float s = 0.f;
    for (int r = blockIdx.x; r < GEMM_BLOCKS; r += RED_BLOCKS)
        s += pb[(size_t)r * 256 + t];
    atomicAdd(&st[t], s);
}

// ---------------- global mean pool with folded BN affine (last layer, no relu) ----------------
static __device__ int lbound(const int* __restrict__ a, int n, int key) {
    int lo = 0, hi = n;
    while (lo < hi) {
        int mid = (lo + hi) >> 1;
        if (a[mid] < key) lo = mid + 1; else hi = mid;
    }
    return lo;
}

__global__ __launch_bounds__(128) void k_pool(const _Float16* __restrict__ Z, const int* __restrict__ batch,
                                              const float* __restrict__ st, const float* __restrict__ gamma,
                                              const float* __restrict__ beta, float* __restrict__ out) {
    __shared__ int bnds[2];
    int g = blockIdx.x, c = threadIdx.x;
    if (threadIdx.x == 0) {
        bnds[0] = lbound(batch, N_NODESC, g);
        bnds[1] = lbound(batch, N_NODESC, g + 1);
    }
    __syncthreads();
    const float invN = 1.f / (float)N_NODESC;
    float m = st[c] * invN;
    float v = st[DF + c] * invN - m * m;
    float sc = gamma[c] * rsqrtf(v + BN_EPSF);
    float of = beta[c] - m * sc;
    int lo = bnds[0], hi = bnds[1];
    float s = 0.f;
    for (int r = lo; r < hi; r++) s += (float)Z[(size_t)r * DF + c];
    int cnt = hi - lo;
    out[g * DF + c] = (cnt > 0) ? (s / (float)cnt) * sc + of : 0.f;
}

extern "C" void kernel_launch(void* const* d_in, const int* in_sizes, int n_in,
                              void* d_out, int out_size, void* d_ws, size_t ws_size,
                              hipStream_t stream) {
    const float* x     = (const float*)d_in[0];
    const int*   ei    = (const int*)d_in[1];   // (2, E): row0=src, row1=dst
    const int*   batch = (const int*)d_in[2];
    const float* W1    = (const float*)d_in[3];
    const float* b1    = (const float*)d_in[4];
    const float* W2    = (const float*)d_in[5];
    const float* b2    = (const float*)d_in[6];
    const float* eps   = (const float*)d_in[7];
    const float* gamma = (const float*)d_in[8];
    const float* beta  = (const float*)d_in[9];
    float* out = (float*)d_out;

    char* ws = (char*)d_ws;
    size_t o = 0;
    auto alloc = [&](size_t bytes) -> char* {
        char* p = ws + o;
        o += (bytes + 255) & ~(size_t)255;
        return p;
    };
    int* off       = (int*)alloc((N_NODESC + 1) * sizeof(int));
    int* cursor    = (int*)alloc(N_NODESC * sizeof(int));
    int* csr       = (int*)alloc(N_EDGESC * sizeof(int));
    int* partials  = (int*)alloc(64 * sizeof(int));
    float* st      = (float*)alloc(3 * 2 * DF * sizeof(float));   // st[l] = st + l*256
    float* pb      = (float*)alloc((size_t)GEMM_BLOCKS * 256 * sizeof(float));  // 3.2 MB
    half8* wf      = (half8*)alloc((size_t)6 * 2048 * sizeof(half8));
    _Float16* hbuf = (_Float16*)alloc((size_t)N_NODESC * DF * sizeof(_Float16));
    _Float16* abuf = (_Float16*)alloc((size_t)N_NODESC * DF * sizeof(_Float16));
    _Float16* za   = (_Float16*)alloc((size_t)N_NODESC * DF * sizeof(_Float16));
    _Float16* zb   = (_Float16*)alloc((size_t)N_NODESC * DF * sizeof(_Float16));
    (void)ws_size; (void)in_sizes; (void)n_in; (void)out_size;

    const int* srcA = ei;
    const int* dstA = ei + N_EDGESC;

    const int NB_SCAN = (N_NODESC + 1023) / 1024;  // 49

    // off must be zero before k_prep's count
    hipMemsetAsync(off, 0, (N_NODESC + 1) * sizeof(int), stream);
    // fused: count | convX | convW | st zero
    k_prep<<<PREP_TOTAL_B, 256, 0, stream>>>(dstA, off, x, hbuf, W1, W2, wf, st);
    k_scan1<<<NB_SCAN, 1024, 0, stream>>>(off, partials);
    k_scanfin<<<NB_SCAN, 1024, 0, stream>>>(off, partials, cursor);
    k_scatter<<<N_EDGESC / 256, 256, 0, stream>>>(srcA, dstA, cursor, csr);

    const int GATHER_GRID = N_NODESC / 4;   // 12500

    // layer 0
    k_gather_bn<0><<<GATHER_GRID, 256, 0, stream>>>(hbuf, off, csr, eps, 0,
                                                    nullptr, nullptr, nullptr, abuf);
    k_gemm12<<<GEMM_BLOCKS, 128, 0, stream>>>(abuf, wf + 0 * 2048, b1 + 0 * DF,
                                              wf + 3 * 2048, b2 + 0 * DF, za, pb);
    k_redstats<<<RED_BLOCKS, 256, 0, stream>>>(pb, st + 0 * 256);
    // layer 1 (bn0+relu folded into gather)
    k_gather_bn<1><<<GATHER_GRID, 256, 0, stream>>>(za, off, csr, eps, 1,
                                                    st + 0 * 256, gamma + 0 * DF, beta + 0 * DF, abuf);
    k_gemm12<<<GEMM_BLOCKS, 128, 0, stream>>>(abuf, wf + 1 * 2048, b1 + 1 * DF,
                                              wf + 4 * 2048, b2 + 1 * DF, zb, pb);
    k_redstats<<<RED_BLOCKS, 256, 0, stream>>>(pb, st + 1 * 256);
    // layer 2 (bn1+relu folded into gather)
    k_gather_bn<1><<<GATHER_GRID, 256, 0, stream>>>(zb, off, csr, eps, 2,
                                                    st + 1 * 256, gamma + 1 * DF, beta + 1 * DF, abuf);
    k_gemm12<<<GEMM_BLOCKS, 128, 0, stream>>>(abuf, wf + 2 * 2048, b1 + 2 * DF,
                                              wf + 5 * 2048, b2 + 2 * DF, za, pb);
    k_redstats<<<RED_BLOCKS, 256, 0, stream>>>(pb, st + 2 * 256);
    // pool with folded bn2 (no relu)
    k_pool<<<N_GRAPHSC, DF, 0, stream>>>(za, batch, st + 2 * 256, gamma + 2 * DF, beta + 2 * DF, out);
}